// Round 4
// baseline (422.018 us; speedup 1.0000x reference)
//
#include <hip/hip_runtime.h>
#include <hip/hip_cooperative_groups.h>
#include <hip/hip_bf16.h>

// ---------------------------------------------------------------------------
// MPS contraction, N=512 sites, D_PHY=4, D_BOND=128, VOC=1024.
// Faithful computation with EXACT all-zero early exit (state underflows to
// exact 0 after ~15 sites; site map is linear, so remaining sites stay 0).
// Round-4 change: the single-line grid barrier (128 RMWs + 128 pollers on ONE
// L3 line -> bank-saturating spin contention, ~15 us/site) is replaced by a
// 3-level tree barrier: 8 group lines (16 arrivals + 15 pollers each) + one
// global line (8 arrivals + 7 pollers). Epoch-versioned monotonic counters,
// liveness delta carried per epoch. Everything else as round 3.
// ---------------------------------------------------------------------------

__device__ __forceinline__ float2 cfma(float2 a, float2 b, float2 acc) {
    acc.x = fmaf(a.x, b.x, fmaf(-a.y, b.y, acc.x));
    acc.y = fmaf(a.x, b.y, fmaf( a.y, b.x, acc.y));
    return acc;
}
__device__ __forceinline__ float2 cfmac(float2 a, float2 b, float2 acc) {
    // acc + conj(a)*b
    acc.x = fmaf(a.x, b.x, fmaf( a.y, b.y, acc.x));
    acc.y = fmaf(a.x, b.y, fmaf(-a.y, b.x, acc.y));
    return acc;
}

// coherent (cache-bypassing) 8-byte load/store for the S exchange
__device__ __forceinline__ float2 ld_coh(const float2* p) {
    union { unsigned long long u; float2 f; } cv;
    cv.u = __hip_atomic_load((const unsigned long long*)p,
                             __ATOMIC_RELAXED, __HIP_MEMORY_SCOPE_AGENT);
    return cv.f;
}
__device__ __forceinline__ void st_coh(float2* p, float2 x) {
    union { unsigned long long u; float2 f; } cv;
    cv.f = x;
    __hip_atomic_store((unsigned long long*)p, cv.u,
                       __ATOMIC_RELAXED, __HIP_MEMORY_SCOPE_AGENT);
}

__device__ __forceinline__ unsigned ld_rlx(const unsigned* p) {
    return __hip_atomic_load(p, __ATOMIC_RELAXED, __HIP_MEMORY_SCOPE_AGENT);
}
__device__ __forceinline__ void st_rlx(unsigned* p, unsigned v) {
    __hip_atomic_store(p, v, __ATOMIC_RELAXED, __HIP_MEMORY_SCOPE_AGENT);
}

__device__ __forceinline__ double2 d2mul(double2 a, double2 b) {
    return make_double2(a.x*b.x - a.y*b.y, a.x*b.y + a.y*b.x);
}
__device__ __forceinline__ double2 d2conj(double2 a) { return make_double2(a.x, -a.y); }

// block reduction over 512 threads (8 waves), deterministic
__device__ double2 qr_blk_red(double2 v, double2* red) {
    for (int off = 32; off; off >>= 1) {
        v.x += __shfl_down(v.x, off, 64);
        v.y += __shfl_down(v.y, off, 64);
    }
    const int wid = threadIdx.x >> 6, lane = threadIdx.x & 63;
    __syncthreads();
    if (lane == 0) red[wid] = v;
    __syncthreads();
    double2 r = make_double2(0.0, 0.0);
    for (int w = 0; w < 8; ++w) { r.x += red[w].x; r.y += red[w].y; }
    return r;
}

// ---------------------------------------------------------------------------
// Kernel 1: Householder QR of A (4096 x 4 complex), LAPACK clarfg/cungqr
// convention (beta real, sign rule pins the column phases M depends on).
// ---------------------------------------------------------------------------
__global__ __launch_bounds__(512) void qr_kernel(const float* __restrict__ a_re,
                                                 const float* __restrict__ a_im,
                                                 float2* __restrict__ Q)
{
    const int t = threadIdx.x;
    __shared__ double2 red[8];
    __shared__ double2 bc;

    float2 a[8][4];
    for (int i = 0; i < 8; ++i) {
        int r = t + 512 * i;
        for (int j = 0; j < 4; ++j)
            a[i][j] = make_float2(a_re[r*4 + j], a_im[r*4 + j]);
    }
    double2 tau[4];

    for (int k = 0; k < 4; ++k) {
        if (t == k) bc = make_double2((double)a[0][k].x, (double)a[0][k].y);
        __syncthreads();
        const double ar = bc.x, ai = bc.y;

        double xn = 0.0;
        for (int i = 0; i < 8; ++i) {
            int r = t + 512 * i;
            if (r > k) xn += (double)a[i][k].x * a[i][k].x + (double)a[i][k].y * a[i][k].y;
        }
        xn = qr_blk_red(make_double2(xn, 0.0), red).x;

        double2 tk, scale;
        if (xn == 0.0 && ai == 0.0) {
            tk = make_double2(0.0, 0.0);
            scale = make_double2(0.0, 0.0);
        } else {
            double nrm = sqrt(ar*ar + ai*ai + xn);
            double beta = (ar >= 0.0) ? -nrm : nrm;       // clarfg sign rule
            tk = make_double2((beta - ar) / beta, -ai / beta);
            double dr = ar - beta, di = ai;
            double dd = dr*dr + di*di;
            scale = make_double2(dr / dd, -di / dd);      // 1/(alpha-beta)
        }
        tau[k] = tk;

        for (int i = 0; i < 8; ++i) {
            int r = t + 512 * i;
            if (r == k) a[i][k] = make_float2(1.f, 0.f);
            else if (r > k) {
                double2 v = d2mul(make_double2(a[i][k].x, a[i][k].y), scale);
                a[i][k] = make_float2((float)v.x, (float)v.y);
            } else a[i][k] = make_float2(0.f, 0.f);
        }
        __syncthreads();

        for (int j = k + 1; j < 4; ++j) {
            double2 w = make_double2(0.0, 0.0);
            for (int i = 0; i < 8; ++i) {
                double2 vv = make_double2(a[i][k].x, a[i][k].y);
                double2 aa = make_double2(a[i][j].x, a[i][j].y);
                double2 m = d2mul(d2conj(vv), aa);
                w.x += m.x; w.y += m.y;
            }
            w = qr_blk_red(w, red);
            double2 cw = d2mul(d2conj(tk), w);
            for (int i = 0; i < 8; ++i) {
                double2 vv = make_double2(a[i][k].x, a[i][k].y);
                double2 upd = d2mul(cw, vv);
                a[i][j] = make_float2((float)((double)a[i][j].x - upd.x),
                                      (float)((double)a[i][j].y - upd.y));
            }
        }
    }

    float2 q[8][4];
    for (int i = 0; i < 8; ++i) {
        int r = t + 512 * i;
        for (int j = 0; j < 4; ++j)
            q[i][j] = make_float2((r == j) ? 1.f : 0.f, 0.f);
    }
    for (int k = 3; k >= 0; --k) {
        for (int j = k; j < 4; ++j) {
            double2 w = make_double2(0.0, 0.0);
            for (int i = 0; i < 8; ++i) {
                double2 vv = make_double2(a[i][k].x, a[i][k].y);
                double2 qq = make_double2(q[i][j].x, q[i][j].y);
                double2 m = d2mul(d2conj(vv), qq);
                w.x += m.x; w.y += m.y;
            }
            w = qr_blk_red(w, red);
            double2 cw = d2mul(tau[k], w);
            for (int i = 0; i < 8; ++i) {
                double2 vv = make_double2(a[i][k].x, a[i][k].y);
                double2 upd = d2mul(cw, vv);
                q[i][j] = make_float2((float)((double)q[i][j].x - upd.x),
                                      (float)((double)q[i][j].y - upd.y));
            }
        }
    }
    for (int i = 0; i < 8; ++i) {
        int r = t + 512 * i;
        for (int j = 0; j < 4; ++j) Q[r*4 + j] = q[i][j];
    }
}

// ---------------------------------------------------------------------------
// Kernel 2: Ms[t][j][k] = sum_i conj(Q[4v+i,j]) Q[4v+i,k], v=tokens[t];
// zeroes the barrier lines (fresh every replay).
// ---------------------------------------------------------------------------
__global__ __launch_bounds__(256) void ms_kernel(const float2* __restrict__ Q,
                                                 const int* __restrict__ tokens,
                                                 float2* __restrict__ Ms,
                                                 unsigned int* __restrict__ cnt)
{
    const int idx = blockIdx.x * 256 + threadIdx.x;   // 32 blocks -> 8192
    if (idx < 8192) {
        const int ti = idx >> 4, jk = idx & 15, j = jk >> 2, kk = jk & 3;
        const int v = tokens[ti];
        float2 s = make_float2(0.f, 0.f);
        for (int i = 0; i < 4; ++i) {
            float2 q1 = Q[(v*4 + i)*4 + j];
            float2 q2 = Q[(v*4 + i)*4 + kk];
            s.x += q1.x*q2.x + q1.y*q2.y;     // conj(q1)*q2
            s.y += q1.x*q2.y - q1.y*q2.x;
        }
        Ms[idx] = s;
    }
    if (idx < 512) cnt[idx] = 0u;
}

// ---------------------------------------------------------------------------
// 3-level tree barrier with per-epoch liveness, fence-free, contention-free.
// Layout (uint words, 32-word = 128 B lines):
//   line 0        (cnt[0..2])          : global arrival | go_global | prev-nz
//   line 1+g, g<8 (cnt[32*(1+g)+0..2]) : group arrival  | group go  | prev-nz
// All words are MONOTONIC across epochs (no resets, no reuse hazards):
//   arrival word: low16 = cumulative count (16/epoch group, 8/epoch global),
//                 high16 = cumulative nz count; per-epoch liveness = delta vs
//                 word[2] (written by the unique last-arriver of each epoch,
//                 with s_waitcnt vmcnt(0) before the downstream signal).
//   go words: low16 = epoch+1, bit16 = live. Unique writer per epoch.
// Pollers per line <= 15; arrivals never queue behind a poll flood.
// ---------------------------------------------------------------------------
__device__ __forceinline__ bool site_barrier(unsigned int* cnt, int e,
                                             unsigned* nzw, int* live_lds,
                                             int tid, int grp)
{
    __syncthreads();            // emits s_waitcnt vmcnt(0): S stores are acked
    if (tid == 0) {
        const unsigned my_nz = (nzw[0] | nzw[1]) ? 1u : 0u;
        unsigned* garr = cnt + 32 * (1 + grp);
        unsigned old = __hip_atomic_fetch_add(garr, 1u | (my_nz << 16),
                          __ATOMIC_RELAXED, __HIP_MEMORY_SCOPE_AGENT);
        int live;
        if ((old & 0xffffu) == (unsigned)(e * 16 + 15)) {
            // ---- group-last arriver
            unsigned cum  = (old >> 16) + my_nz;
            unsigned prev = ld_rlx(garr + 2);
            unsigned glive = (cum != prev) ? 1u : 0u;
            st_rlx(garr + 2, cum);
            asm volatile("s_waitcnt vmcnt(0)" ::: "memory");
            unsigned gold = __hip_atomic_fetch_add(cnt, 1u | (glive << 16),
                              __ATOMIC_RELAXED, __HIP_MEMORY_SCOPE_AGENT);
            if ((gold & 0xffffu) == (unsigned)(e * 8 + 7)) {
                // ---- global-last arriver
                unsigned gcum  = (gold >> 16) + glive;
                unsigned gprev = ld_rlx(cnt + 2);
                live = (gcum != gprev) ? 1 : 0;
                st_rlx(cnt + 2, gcum);
                asm volatile("s_waitcnt vmcnt(0)" ::: "memory");
                st_rlx(cnt + 1, (unsigned)(e + 1) | (live ? 0x10000u : 0u));
            } else {
                unsigned gv;
                for (;;) {
                    gv = ld_rlx(cnt + 1);
                    if ((gv & 0xffffu) == (unsigned)(e + 1)) break;
                    __builtin_amdgcn_s_sleep(1);
                }
                live = (gv >> 16) & 1;
            }
            st_rlx(garr + 1, (unsigned)(e + 1) | (live ? 0x10000u : 0u));
        } else {
            unsigned gv;
            for (;;) {
                gv = ld_rlx(garr + 1);
                if ((gv & 0xffffu) == (unsigned)(e + 1)) break;
                __builtin_amdgcn_s_sleep(1);
            }
            live = (gv >> 16) & 1;
        }
        *live_lds = live;
    }
    __syncthreads();
    return *live_lds != 0;
}

// ---------------------------------------------------------------------------
// Kernel 3: site 0 (folded) + cooperative scan t=1..510 + final site.
// 128 wgs x 512 threads; wg owns output column c (XCD-grouped mapping).
// Per site: C[p][b] = sum_q M[p,q] B[q,b,c]        (prefetched regs -> LDS)
//           U[p][a] = sum_b S[a,b] C[p][b]          (quarter-split b)
//           S'[r,c] = sum_pa conj(B[p,a,r]) U[pa]   (quarter-split pa)
// ---------------------------------------------------------------------------
__global__ __launch_bounds__(512) void scan_kernel(
    const float* __restrict__ bm_re, const float* __restrict__ bm_im,
    const float* __restrict__ b0_re, const float* __restrict__ b0_im,
    const float* __restrict__ bl_re, const float* __restrict__ bl_im,
    const float2* __restrict__ Ms,
    float2* SbufA, float2* SbufB,
    unsigned int* cnt, float* out, int out_size)
{
    const int tid = threadIdx.x;
    const int bid = blockIdx.x;
    const int grp = bid & 7;                       // barrier group = XCD
    const int c = ((bid & 7) << 4) | (bid >> 3);   // same-XCD wgs -> adjacent c

    __shared__ float2 Clds[4][128];
    __shared__ float2 Upart[4][512];
    __shared__ float2 U[512];
    __shared__ float2 red4[4][128];
    __shared__ float2 fred[8];
    __shared__ unsigned nzw[2];
    __shared__ int live_lds;

    const int a = tid & 127;
    const int h = tid >> 7;          // quarter id 0..3 (2 waves per quarter)

    float2* Sread = SbufA;
    float2* Swrite = SbufB;
    bool dead = false;

    // ---- site 0: threads h==0 compute column c of S0 (transposed store)
    if (h == 0) {
        const int r = a;
        float2 brr[4], bcc[4];
        for (int p = 0; p < 4; ++p) {
            brr[p] = make_float2(b0_re[p*128 + r], b0_im[p*128 + r]);
            bcc[p] = make_float2(b0_re[p*128 + c], b0_im[p*128 + c]);
        }
        float2 acc = make_float2(0.f, 0.f);
        for (int p = 0; p < 4; ++p) {
            float2 tp = make_float2(0.f, 0.f);
            for (int q = 0; q < 4; ++q) tp = cfma(Ms[p*4 + q], bcc[q], tp);
            acc = cfmac(brr[p], tp, acc);
        }
        st_coh(&SbufA[c*128 + r], acc);
        int nz = (acc.x != 0.f) || (acc.y != 0.f);
        unsigned long long m = __ballot(nz);
        if ((tid & 63) == 0) nzw[tid >> 6] = (m != 0ULL) ? 1u : 0u;
    }

    // prefetch C-step B values for site t=1
    float prr[4], pri[4];
    {
        const float* brn = bm_re;
        const float* bin = bm_im;
        for (int q = 0; q < 4; ++q) {
            prr[q] = brn[(q*128 + a)*128 + c];
            pri[q] = bin[(q*128 + a)*128 + c];
        }
    }

    if (!site_barrier(cnt, 0, nzw, &live_lds, tid, grp)) dead = true;

    if (!dead) {
        for (int t = 1; t <= 510; ++t) {
            const float2* Mt = Ms + t * 16;
            const float* br = bm_re + (size_t)(t - 1) * 65536;
            const float* bi = bm_im + (size_t)(t - 1) * 65536;

            // ---- C[p][b] from prefetched regs (thread: p=h, b=a)
            {
                float2 acc = make_float2(0.f, 0.f);
                for (int q = 0; q < 4; ++q)
                    acc = cfma(Mt[h*4 + q], make_float2(prr[q], pri[q]), acc);
                Clds[h][a] = acc;
            }
            __syncthreads();

            // ---- issue prefetch for next site (hidden under U/out compute)
            float prr_n[4], pri_n[4];
            if (t < 510) {
                const float* brn = bm_re + (size_t)t * 65536;
                const float* bin = bm_im + (size_t)t * 65536;
                for (int q = 0; q < 4; ++q) {
                    prr_n[q] = brn[(q*128 + a)*128 + c];
                    pri_n[q] = bin[(q*128 + a)*128 + c];
                }
            } else {
                for (int q = 0; q < 4; ++q) { prr_n[q] = 0.f; pri_n[q] = 0.f; }
            }

            // ---- U[p][a] = sum_b S[a,b] C[p][b]; quarter-split b
            float2 u0 = make_float2(0,0), u1 = u0, u2 = u0, u3 = u0;
            #pragma unroll 8
            for (int bb = h * 32; bb < h * 32 + 32; ++bb) {
                float2 s = ld_coh(&Sread[bb * 128 + a]);   // bypass, coalesced
                u0 = cfma(s, Clds[0][bb], u0);
                u1 = cfma(s, Clds[1][bb], u1);
                u2 = cfma(s, Clds[2][bb], u2);
                u3 = cfma(s, Clds[3][bb], u3);
            }
            Upart[h][0*128 + a] = u0;
            Upart[h][1*128 + a] = u1;
            Upart[h][2*128 + a] = u2;
            Upart[h][3*128 + a] = u3;
            __syncthreads();
            {
                float2 x0 = Upart[0][tid], x1 = Upart[1][tid];
                float2 x2 = Upart[2][tid], x3 = Upart[3][tid];
                U[tid] = make_float2(x0.x + x1.x + x2.x + x3.x,
                                     x0.y + x1.y + x2.y + x3.y);
            }
            __syncthreads();

            // ---- S'[r,c] partial: quarter-split pa
            const int r = a;
            float2 o0 = make_float2(0,0), o1 = o0;
            #pragma unroll 4
            for (int pa = h * 128; pa < h * 128 + 128; pa += 2) {
                float2 b1 = make_float2(br[pa*128 + r],     bi[pa*128 + r]);
                float2 b2 = make_float2(br[(pa+1)*128 + r], bi[(pa+1)*128 + r]);
                o0 = cfmac(b1, U[pa],     o0);
                o1 = cfmac(b2, U[pa + 1], o1);
            }
            o0.x += o1.x; o0.y += o1.y;
            red4[h][r] = o0;
            __syncthreads();
            if (h == 0) {
                float2 fin = make_float2(
                    red4[0][r].x + red4[1][r].x + red4[2][r].x + red4[3][r].x,
                    red4[0][r].y + red4[1][r].y + red4[2][r].y + red4[3][r].y);
                st_coh(&Swrite[c * 128 + r], fin);          // write-through
                int nz = (fin.x != 0.f) || (fin.y != 0.f);
                unsigned long long m = __ballot(nz);
                if ((tid & 63) == 0) nzw[tid >> 6] = (m != 0ULL) ? 1u : 0u;
            }
            if (!site_barrier(cnt, t, nzw, &live_lds, tid, grp)) { dead = true; break; }
            float2* tmp = Sread; Sread = Swrite; Swrite = tmp;
            for (int q = 0; q < 4; ++q) { prr[q] = prr_n[q]; pri[q] = pri_n[q]; }
        }
    }

    if (dead) {
        if (bid == 0 && tid == 0) {
            out[0] = 0.f;
            if (out_size > 1) out[1] = 0.f;
        }
        return;
    }
    if (bid != 0) return;

    // ---- final site: Bl (4,128,1), Ms[511]; Sread holds S(510) transposed
    const float2* Mt = Ms + 511 * 16;
    {   // t1[q=h][a] = sum_b S[a,b] * Bl[q,b]
        float2 acc = make_float2(0,0);
        for (int b = 0; b < 128; ++b) {
            float2 s = ld_coh(&Sread[b * 128 + a]);
            float2 bl = make_float2(bl_re[h*128 + b], bl_im[h*128 + b]);
            acc = cfma(s, bl, acc);
        }
        Clds[h][a] = acc;
    }
    __syncthreads();
    float2 tot;
    {
        float2 tp = make_float2(0,0);
        for (int q = 0; q < 4; ++q) tp = cfma(Mt[h*4 + q], Clds[q][a], tp);
        float2 blv = make_float2(bl_re[h*128 + a], bl_im[h*128 + a]);
        tot = cfmac(blv, tp, make_float2(0,0));
    }
    for (int off = 32; off; off >>= 1) {
        tot.x += __shfl_down(tot.x, off, 64);
        tot.y += __shfl_down(tot.y, off, 64);
    }
    if ((tid & 63) == 0) fred[tid >> 6] = tot;
    __syncthreads();
    if (tid == 0) {
        float2 s = make_float2(0,0);
        for (int w = 0; w < 8; ++w) { s.x += fred[w].x; s.y += fred[w].y; }
        out[0] = s.x;
        if (out_size > 1) out[1] = s.y;
    }
}

// ---------------------------------------------------------------------------
extern "C" void kernel_launch(void* const* d_in, const int* in_sizes, int n_in,
                              void* d_out, int out_size, void* d_ws, size_t ws_size,
                              hipStream_t stream)
{
    const float* a_re  = (const float*)d_in[0];
    const float* a_im  = (const float*)d_in[1];
    const float* b0_re = (const float*)d_in[2];
    const float* b0_im = (const float*)d_in[3];
    const float* bm_re = (const float*)d_in[4];
    const float* bm_im = (const float*)d_in[5];
    const float* bl_re = (const float*)d_in[6];
    const float* bl_im = (const float*)d_in[7];
    const int*  tokens = (const int*)d_in[8];

    char* ws = (char*)d_ws;
    float2* Q    = (float2*)(ws);                   // 131072 B
    float2* Ms   = (float2*)(ws + 131072);          //  65536 B
    float2* S0   = (float2*)(ws + 196608);          // 131072 B
    float2* S1b  = (float2*)(ws + 327680);          // 131072 B
    unsigned int* cnt = (unsigned int*)(ws + 458752); // 9 x 128 B lines used

    qr_kernel<<<dim3(1), dim3(512), 0, stream>>>(a_re, a_im, Q);
    ms_kernel<<<dim3(32), dim3(256), 0, stream>>>((const float2*)Q, tokens, Ms, cnt);

    float* outf = (float*)d_out;
    int osz = out_size;
    void* args[] = {
        (void*)&bm_re, (void*)&bm_im, (void*)&b0_re, (void*)&b0_im,
        (void*)&bl_re, (void*)&bl_im,
        (void*)&Ms, (void*)&S0, (void*)&S1b, (void*)&cnt, (void*)&outf, (void*)&osz
    };
    hipLaunchCooperativeKernel((const void*)scan_kernel, dim3(128), dim3(512),
                               args, 0, stream);
}

// Round 5
// 346.270 us; speedup vs baseline: 1.2188x; 1.2188x over previous
//
#include <hip/hip_runtime.h>
#include <hip/hip_bf16.h>

// ---------------------------------------------------------------------------
// MPS contraction, N=512 sites, D_PHY=4, D_BOND=128, VOC=1024.
// Faithful computation with EXACT all-zero early exit (state underflows to
// exact 0 after ~15 sites; site map is linear, so remaining sites stay 0).
// Round-5: flat barrier restored (tree regressed); B-tile L3-warming one site
// ahead (out-step was HBM-cold first touch -> latency + barrier skew);
// Ms table computed per-wg into LDS (ms_kernel deleted, no per-site global
// Ms reads); full-unroll U-step for max MLP.
// ---------------------------------------------------------------------------

__device__ __forceinline__ float2 cfma(float2 a, float2 b, float2 acc) {
    acc.x = fmaf(a.x, b.x, fmaf(-a.y, b.y, acc.x));
    acc.y = fmaf(a.x, b.y, fmaf( a.y, b.x, acc.y));
    return acc;
}
__device__ __forceinline__ float2 cfmac(float2 a, float2 b, float2 acc) {
    // acc + conj(a)*b
    acc.x = fmaf(a.x, b.x, fmaf( a.y, b.y, acc.x));
    acc.y = fmaf(a.x, b.y, fmaf(-a.y, b.x, acc.y));
    return acc;
}

// coherent (cache-bypassing) 8-byte load/store for the S exchange
__device__ __forceinline__ float2 ld_coh(const float2* p) {
    union { unsigned long long u; float2 f; } cv;
    cv.u = __hip_atomic_load((const unsigned long long*)p,
                             __ATOMIC_RELAXED, __HIP_MEMORY_SCOPE_AGENT);
    return cv.f;
}
__device__ __forceinline__ void st_coh(float2* p, float2 x) {
    union { unsigned long long u; float2 f; } cv;
    cv.f = x;
    __hip_atomic_store((unsigned long long*)p, cv.u,
                       __ATOMIC_RELAXED, __HIP_MEMORY_SCOPE_AGENT);
}

__device__ __forceinline__ double2 d2mul(double2 a, double2 b) {
    return make_double2(a.x*b.x - a.y*b.y, a.x*b.y + a.y*b.x);
}
__device__ __forceinline__ double2 d2conj(double2 a) { return make_double2(a.x, -a.y); }

// block reduction over 512 threads (8 waves), deterministic
__device__ double2 qr_blk_red(double2 v, double2* red) {
    for (int off = 32; off; off >>= 1) {
        v.x += __shfl_down(v.x, off, 64);
        v.y += __shfl_down(v.y, off, 64);
    }
    const int wid = threadIdx.x >> 6, lane = threadIdx.x & 63;
    __syncthreads();
    if (lane == 0) red[wid] = v;
    __syncthreads();
    double2 r = make_double2(0.0, 0.0);
    for (int w = 0; w < 8; ++w) { r.x += red[w].x; r.y += red[w].y; }
    return r;
}

// ---------------------------------------------------------------------------
// Kernel 1: Householder QR of A (4096 x 4 complex), LAPACK clarfg/cungqr
// convention (beta real, sign rule pins the column phases M depends on).
// Also zeroes the 512 barrier words (fresh every replay).
// ---------------------------------------------------------------------------
__global__ __launch_bounds__(512) void qr_kernel(const float* __restrict__ a_re,
                                                 const float* __restrict__ a_im,
                                                 float2* __restrict__ Q,
                                                 unsigned int* __restrict__ cnt)
{
    const int t = threadIdx.x;
    cnt[t] = 0u;

    __shared__ double2 red[8];
    __shared__ double2 bc;

    float2 a[8][4];
    for (int i = 0; i < 8; ++i) {
        int r = t + 512 * i;
        for (int j = 0; j < 4; ++j)
            a[i][j] = make_float2(a_re[r*4 + j], a_im[r*4 + j]);
    }
    double2 tau[4];

    for (int k = 0; k < 4; ++k) {
        if (t == k) bc = make_double2((double)a[0][k].x, (double)a[0][k].y);
        __syncthreads();
        const double ar = bc.x, ai = bc.y;

        double xn = 0.0;
        for (int i = 0; i < 8; ++i) {
            int r = t + 512 * i;
            if (r > k) xn += (double)a[i][k].x * a[i][k].x + (double)a[i][k].y * a[i][k].y;
        }
        xn = qr_blk_red(make_double2(xn, 0.0), red).x;

        double2 tk, scale;
        if (xn == 0.0 && ai == 0.0) {
            tk = make_double2(0.0, 0.0);
            scale = make_double2(0.0, 0.0);
        } else {
            double nrm = sqrt(ar*ar + ai*ai + xn);
            double beta = (ar >= 0.0) ? -nrm : nrm;       // clarfg sign rule
            tk = make_double2((beta - ar) / beta, -ai / beta);
            double dr = ar - beta, di = ai;
            double dd = dr*dr + di*di;
            scale = make_double2(dr / dd, -di / dd);      // 1/(alpha-beta)
        }
        tau[k] = tk;

        for (int i = 0; i < 8; ++i) {
            int r = t + 512 * i;
            if (r == k) a[i][k] = make_float2(1.f, 0.f);
            else if (r > k) {
                double2 v = d2mul(make_double2(a[i][k].x, a[i][k].y), scale);
                a[i][k] = make_float2((float)v.x, (float)v.y);
            } else a[i][k] = make_float2(0.f, 0.f);
        }
        __syncthreads();

        for (int j = k + 1; j < 4; ++j) {
            double2 w = make_double2(0.0, 0.0);
            for (int i = 0; i < 8; ++i) {
                double2 vv = make_double2(a[i][k].x, a[i][k].y);
                double2 aa = make_double2(a[i][j].x, a[i][j].y);
                double2 m = d2mul(d2conj(vv), aa);
                w.x += m.x; w.y += m.y;
            }
            w = qr_blk_red(w, red);
            double2 cw = d2mul(d2conj(tk), w);
            for (int i = 0; i < 8; ++i) {
                double2 vv = make_double2(a[i][k].x, a[i][k].y);
                double2 upd = d2mul(cw, vv);
                a[i][j] = make_float2((float)((double)a[i][j].x - upd.x),
                                      (float)((double)a[i][j].y - upd.y));
            }
        }
    }

    float2 q[8][4];
    for (int i = 0; i < 8; ++i) {
        int r = t + 512 * i;
        for (int j = 0; j < 4; ++j)
            q[i][j] = make_float2((r == j) ? 1.f : 0.f, 0.f);
    }
    for (int k = 3; k >= 0; --k) {
        for (int j = k; j < 4; ++j) {
            double2 w = make_double2(0.0, 0.0);
            for (int i = 0; i < 8; ++i) {
                double2 vv = make_double2(a[i][k].x, a[i][k].y);
                double2 qq = make_double2(q[i][j].x, q[i][j].y);
                double2 m = d2mul(d2conj(vv), qq);
                w.x += m.x; w.y += m.y;
            }
            w = qr_blk_red(w, red);
            double2 cw = d2mul(tau[k], w);
            for (int i = 0; i < 8; ++i) {
                double2 vv = make_double2(a[i][k].x, a[i][k].y);
                double2 upd = d2mul(cw, vv);
                q[i][j] = make_float2((float)((double)q[i][j].x - upd.x),
                                      (float)((double)q[i][j].y - upd.y));
            }
        }
    }
    for (int i = 0; i < 8; ++i) {
        int r = t + 512 * i;
        for (int j = 0; j < 4; ++j) Q[r*4 + j] = q[i][j];
    }
}

// ---------------------------------------------------------------------------
// Flat fused grid barrier + liveness, fence-free (round-3 design).
// S stores are write-through (sc0+sc1); __syncthreads() drains vmcnt for
// every wave, so by the time tid 0 adds, this wg's S is globally visible.
// Count field == 128 => word final => liveness bits consistent & uniform.
// ---------------------------------------------------------------------------
#define NWG 128u
__device__ __forceinline__ bool site_barrier(unsigned int* addr,
                                             unsigned* nzw, int* live_lds, int tid)
{
    __syncthreads();                 // drains vmcnt(0) for all waves
    if (tid == 0) {
        unsigned add = 1u | ((nzw[0] | nzw[1]) ? 0x10000u : 0u);
        __hip_atomic_fetch_add(addr, add, __ATOMIC_RELAXED, __HIP_MEMORY_SCOPE_AGENT);
        unsigned v;
        for (;;) {
            v = __hip_atomic_load(addr, __ATOMIC_RELAXED, __HIP_MEMORY_SCOPE_AGENT);
            if ((v & 0xffffu) >= NWG) break;
            __builtin_amdgcn_s_sleep(1);
        }
        *live_lds = (int)(v >> 16);
    }
    __syncthreads();
    return *live_lds != 0;
}

// ---------------------------------------------------------------------------
// Kernel 2: Ms-table prologue + site 0 + cooperative scan t=1..510 + final.
// 128 wgs x 512 threads; wg owns output column c (XCD-grouped mapping).
// Per site: C[p][b] = sum_q M[p,q] B[q,b,c]        (prefetched regs -> LDS)
//           U[p][a] = sum_b S[a,b] C[p][b]          (quarter-split b)
//           S'[r,c] = sum_pa conj(B[p,a,r]) U[pa]   (quarter-split pa)
// Plus: cooperative L3-warming of tile t (used at t+1) each iteration.
// ---------------------------------------------------------------------------
__global__ __launch_bounds__(512) void scan_kernel(
    const float* __restrict__ bm_re, const float* __restrict__ bm_im,
    const float* __restrict__ b0_re, const float* __restrict__ b0_im,
    const float* __restrict__ bl_re, const float* __restrict__ bl_im,
    const float2* __restrict__ Q, const int* __restrict__ tokens,
    float2* SbufA, float2* SbufB,
    unsigned int* cnt, float* out, int out_size)
{
    const int tid = threadIdx.x;
    const int bid = blockIdx.x;
    const int c = ((bid & 7) << 4) | (bid >> 3);   // same-XCD wgs -> adjacent c

    __shared__ float2 MsL[8192];       // 64 KB: full per-site op table
    __shared__ float2 Clds[4][128];
    __shared__ float2 Upart[4][512];
    __shared__ float2 U[512];
    __shared__ float2 red4[4][128];
    __shared__ float2 fred[8];
    __shared__ unsigned nzw[2];
    __shared__ int live_lds;

    const int a = tid & 127;
    const int h = tid >> 7;          // quarter id 0..3 (2 waves per quarter)

    float2* Sread = SbufA;
    float2* Swrite = SbufB;
    bool dead = false;
    float warmacc = 0.f;

    // ---- warm tile 0 (used by out-step at t=1) while Ms table is built
    {
        const int g  = (c << 9) | tid;           // 65536 threads cover tile
        const int g2 = (g + 32768) & 65535;
        warmacc += bm_re[g] + bm_im[g] + bm_re[g2] + bm_im[g2];
    }

    // ---- Ms table: MsL[t*16 + j*4+k] = sum_i conj(Q[4v+i,j]) Q[4v+i,k]
    for (int kk16 = 0; kk16 < 16; ++kk16) {
        const int idx = tid + 512 * kk16;        // 0..8191
        const int ti = idx >> 4, jk = idx & 15, j = jk >> 2, kk = jk & 3;
        const int v = tokens[ti];
        float2 s = make_float2(0.f, 0.f);
        for (int i = 0; i < 4; ++i) {
            float2 q1 = Q[(v*4 + i)*4 + j];
            float2 q2 = Q[(v*4 + i)*4 + kk];
            s.x += q1.x*q2.x + q1.y*q2.y;        // conj(q1)*q2
            s.y += q1.x*q2.y - q1.y*q2.x;
        }
        MsL[idx] = s;
    }
    __syncthreads();

    // ---- site 0: threads h==0 compute column c of S0 (transposed store)
    if (h == 0) {
        const int r = a;
        float2 brr[4], bcc[4];
        for (int p = 0; p < 4; ++p) {
            brr[p] = make_float2(b0_re[p*128 + r], b0_im[p*128 + r]);
            bcc[p] = make_float2(b0_re[p*128 + c], b0_im[p*128 + c]);
        }
        float2 acc = make_float2(0.f, 0.f);
        for (int p = 0; p < 4; ++p) {
            float2 tp = make_float2(0.f, 0.f);
            for (int q = 0; q < 4; ++q) tp = cfma(MsL[p*4 + q], bcc[q], tp);
            acc = cfmac(brr[p], tp, acc);
        }
        st_coh(&SbufA[c*128 + r], acc);
        int nz = (acc.x != 0.f) || (acc.y != 0.f);
        unsigned long long m = __ballot(nz);
        if ((tid & 63) == 0) nzw[tid >> 6] = (m != 0ULL) ? 1u : 0u;
    }

    // prefetch C-step B values for site t=1
    float prr[4], pri[4];
    for (int q = 0; q < 4; ++q) {
        prr[q] = bm_re[(q*128 + a)*128 + c];
        pri[q] = bm_im[(q*128 + a)*128 + c];
    }

    if (!site_barrier(&cnt[0], nzw, &live_lds, tid)) dead = true;

    if (!dead) {
        for (int t = 1; t <= 510; ++t) {
            const float2* Mt = MsL + t * 16;
            const float* br = bm_re + (size_t)(t - 1) * 65536;
            const float* bi = bm_im + (size_t)(t - 1) * 65536;

            // ---- issue warm loads for tile t (used by out-step at t+1)
            float w0 = 0.f, w1 = 0.f, w2 = 0.f, w3 = 0.f;
            if (t < 510) {
                const float* wr = bm_re + (size_t)t * 65536;
                const float* wi = bm_im + (size_t)t * 65536;
                const int g  = (c << 9) | tid;
                const int g2 = (g + 32768) & 65535;
                w0 = wr[g]; w1 = wi[g]; w2 = wr[g2]; w3 = wi[g2];
            }

            // ---- C[p][b] from prefetched regs (thread: p=h, b=a)
            {
                float2 acc = make_float2(0.f, 0.f);
                for (int q = 0; q < 4; ++q)
                    acc = cfma(Mt[h*4 + q], make_float2(prr[q], pri[q]), acc);
                Clds[h][a] = acc;
            }
            __syncthreads();

            // ---- issue prefetch for next site's C-step (drains at barrier)
            float prr_n[4], pri_n[4];
            if (t < 510) {
                const float* brn = bm_re + (size_t)t * 65536;
                const float* bin = bm_im + (size_t)t * 65536;
                for (int q = 0; q < 4; ++q) {
                    prr_n[q] = brn[(q*128 + a)*128 + c];
                    pri_n[q] = bin[(q*128 + a)*128 + c];
                }
            } else {
                for (int q = 0; q < 4; ++q) { prr_n[q] = 0.f; pri_n[q] = 0.f; }
            }

            // ---- U[p][a] = sum_b S[a,b] C[p][b]; quarter-split b, full MLP
            float2 u0 = make_float2(0,0), u1 = u0, u2 = u0, u3 = u0;
            #pragma unroll
            for (int bb = h * 32; bb < h * 32 + 32; ++bb) {
                float2 s = ld_coh(&Sread[bb * 128 + a]);   // bypass, coalesced
                u0 = cfma(s, Clds[0][bb], u0);
                u1 = cfma(s, Clds[1][bb], u1);
                u2 = cfma(s, Clds[2][bb], u2);
                u3 = cfma(s, Clds[3][bb], u3);
            }
            Upart[h][0*128 + a] = u0;
            Upart[h][1*128 + a] = u1;
            Upart[h][2*128 + a] = u2;
            Upart[h][3*128 + a] = u3;
            __syncthreads();
            {
                float2 x0 = Upart[0][tid], x1 = Upart[1][tid];
                float2 x2 = Upart[2][tid], x3 = Upart[3][tid];
                U[tid] = make_float2(x0.x + x1.x + x2.x + x3.x,
                                     x0.y + x1.y + x2.y + x3.y);
            }
            __syncthreads();

            // ---- S'[r,c] partial: quarter-split pa (tile is L2/L3-warm)
            const int r = a;
            float2 o0 = make_float2(0,0), o1 = o0;
            #pragma unroll 8
            for (int pa = h * 128; pa < h * 128 + 128; pa += 2) {
                float2 b1 = make_float2(br[pa*128 + r],     bi[pa*128 + r]);
                float2 b2 = make_float2(br[(pa+1)*128 + r], bi[(pa+1)*128 + r]);
                o0 = cfmac(b1, U[pa],     o0);
                o1 = cfmac(b2, U[pa + 1], o1);
            }
            o0.x += o1.x; o0.y += o1.y;
            red4[h][r] = o0;
            __syncthreads();
            if (h == 0) {
                float2 fin = make_float2(
                    red4[0][r].x + red4[1][r].x + red4[2][r].x + red4[3][r].x,
                    red4[0][r].y + red4[1][r].y + red4[2][r].y + red4[3][r].y);
                st_coh(&Swrite[c * 128 + r], fin);          // write-through
                int nz = (fin.x != 0.f) || (fin.y != 0.f);
                unsigned long long m = __ballot(nz);
                if ((tid & 63) == 0) nzw[tid >> 6] = (m != 0ULL) ? 1u : 0u;
            }
            warmacc += w0 + w1 + w2 + w3;     // keep warm loads live

            if (!site_barrier(&cnt[t], nzw, &live_lds, tid)) { dead = true; break; }
            float2* tmp = Sread; Sread = Swrite; Swrite = tmp;
            for (int q = 0; q < 4; ++q) { prr[q] = prr_n[q]; pri[q] = pri_n[q]; }
        }
    }

    if (out_size < 0) out[2] = warmacc;        // never true: keeps warm loads

    if (dead) {
        if (bid == 0 && tid == 0) {
            out[0] = 0.f;
            if (out_size > 1) out[1] = 0.f;
        }
        return;
    }
    if (bid != 0) return;

    // ---- final site: Bl (4,128,1), Ms[511]; Sread holds S(510) transposed
    const float2* Mt = MsL + 511 * 16;
    {   // t1[q=h][a] = sum_b S[a,b] * Bl[q,b]
        float2 acc = make_float2(0,0);
        for (int b = 0; b < 128; ++b) {
            float2 s = ld_coh(&Sread[b * 128 + a]);
            float2 bl = make_float2(bl_re[h*128 + b], bl_im[h*128 + b]);
            acc = cfma(s, bl, acc);
        }
        Clds[h][a] = acc;
    }
    __syncthreads();
    float2 tot;
    {
        float2 tp = make_float2(0,0);
        for (int q = 0; q < 4; ++q) tp = cfma(Mt[h*4 + q], Clds[q][a], tp);
        float2 blv = make_float2(bl_re[h*128 + a], bl_im[h*128 + a]);
        tot = cfmac(blv, tp, make_float2(0,0));
    }
    for (int off = 32; off; off >>= 1) {
        tot.x += __shfl_down(tot.x, off, 64);
        tot.y += __shfl_down(tot.y, off, 64);
    }
    if ((tid & 63) == 0) fred[tid >> 6] = tot;
    __syncthreads();
    if (tid == 0) {
        float2 s = make_float2(0,0);
        for (int w = 0; w < 8; ++w) { s.x += fred[w].x; s.y += fred[w].y; }
        out[0] = s.x;
        if (out_size > 1) out[1] = s.y;
    }
}

// ---------------------------------------------------------------------------
extern "C" void kernel_launch(void* const* d_in, const int* in_sizes, int n_in,
                              void* d_out, int out_size, void* d_ws, size_t ws_size,
                              hipStream_t stream)
{
    const float* a_re  = (const float*)d_in[0];
    const float* a_im  = (const float*)d_in[1];
    const float* b0_re = (const float*)d_in[2];
    const float* b0_im = (const float*)d_in[3];
    const float* bm_re = (const float*)d_in[4];
    const float* bm_im = (const float*)d_in[5];
    const float* bl_re = (const float*)d_in[6];
    const float* bl_im = (const float*)d_in[7];
    const int*  tokens = (const int*)d_in[8];

    char* ws = (char*)d_ws;
    float2* Q    = (float2*)(ws);                     // 131072 B
    float2* S0   = (float2*)(ws + 196608);            // 131072 B
    float2* S1b  = (float2*)(ws + 327680);            // 131072 B
    unsigned int* cnt = (unsigned int*)(ws + 458752); // 2048 B

    qr_kernel<<<dim3(1), dim3(512), 0, stream>>>(a_re, a_im, Q, cnt);

    float* outf = (float*)d_out;
    int osz = out_size;
    void* args[] = {
        (void*)&bm_re, (void*)&bm_im, (void*)&b0_re, (void*)&b0_im,
        (void*)&bl_re, (void*)&bl_im,
        (void*)&Q, (void*)&tokens,
        (void*)&S0, (void*)&S1b, (void*)&cnt, (void*)&outf, (void*)&osz
    };
    hipLaunchCooperativeKernel((const void*)scan_kernel, dim3(128), dim3(512),
                               args, 0, stream);
}